// Round 12
// baseline (265.631 us; speedup 1.0000x reference)
//
#include <hip/hip_runtime.h>
#include <stdint.h>

// GAT layer on MI355X: B=8, N=2048, F=128.
// h = x@W^T ; s1=h@a1 ; s2=h@a2 ; e=leaky(s1[i]+s2[j]); masked softmax; out=attn@h
// Scores rank-1. adj read exactly once (134 MB, ~21 us floor) in attn.
//
// R12: gat_attn v4 — barrier-free main loop. hT (512 KB/batch, L2-resident
// under b=bid&7) is gathered straight from global per MFMA B-frag; no LDS
// staging, no per-chunk __syncthreads (R9-R11's ~60us was barrier-serialized
// staging latency at 2 blk/CU). 1024 blocks x 256 thr; block = (b, 16 rows);
// wave = j-quarter (8 chunks of 64 j). Combine 4 quarters via LDS once.
// gat_h = R11 v3 (512 blocks, 32 rows, no W LDS, ~10 us).

#define B_ 8
#define N_ 2048
#define FD 128
#define ALPHA_ 0.2f
#define CHUNK_U4 1024             // 128 o x 8 u4 per 64-j chunk (16 KB)

typedef __attribute__((ext_vector_type(8))) short short8;
typedef __attribute__((ext_vector_type(4))) float f32x4;

// 3-bit XOR swizzle for 128x64 hT chunks (uint4 units): row o, 16B-chunk jc(0..7)
#define HC64(o, jc) ((o) * 8 + ((jc) ^ ((o) & 7)))              // uint4 index

__device__ __forceinline__ float bf2f(unsigned short u) {
    union { uint32_t i; float f; } v; v.i = ((uint32_t)u) << 16; return v.f;
}
__device__ __forceinline__ unsigned short f2bf(float f) {
    union { float f; uint32_t i; } v; v.f = f;
    uint32_t x = v.i;
    uint32_t r = (x + 0x7fffu + ((x >> 16) & 1u)) >> 16;  // RNE
    return (unsigned short)r;
}

// ---------------------------------------------------------------------------
// Kernel 1 v3 (R11): h = x@W^T, 512 blocks x 256 thr, 32 rows/block.
// Wave (oh=w>>1, rh=w&1): rows [rh*16,+16) local, o in [oh*64,+64).
// C/D: col=lane&15 (o), row=quad*4+reg (m89/m91-verified).
// ---------------------------------------------------------------------------
__global__ __launch_bounds__(256, 4) void gat_h(
    const float* __restrict__ x,
    const float* __restrict__ W,
    const float* __restrict__ a,
    unsigned short* __restrict__ hT,   // chunked: [b][kc][HC64(o,jc)*8+(j&7)]
    float* __restrict__ s1o, float* __restrict__ s2o)
{
    __shared__ __align__(16) uint4 xs[32][32];   // 16 KB, chunk c ^ row
    __shared__ float s1c[2][32], s2c[2][32];     // o-half partials

    const int bid = blockIdx.x;
    const int tid = threadIdx.x;
    const int w = tid >> 6;
    const int lane = tid & 63;
    const int oh = w >> 1;
    const int rh = w & 1;
    const int m = lane & 15;
    const int quad = lane >> 4;

    // ---- stage x tile (32 rows x 128 f fp32 = 16 KB) coalesced ----
#pragma unroll
    for (int it = 0; it < 4; it++) {
        int idx = it * 256 + tid;          // 1024 uint4
        int row = idx >> 5, c = idx & 31;
        uint4 v = *(const uint4*)(x + (size_t)bid * 4096 + (size_t)idx * 4);
        xs[row][c ^ row] = v;
    }
    __syncthreads();

    f32x4 acc[4];
#pragma unroll
    for (int ot = 0; ot < 4; ot++) acc[ot] = (f32x4){0.f, 0.f, 0.f, 0.f};

    const int xrow = rh * 16 + m;
#pragma unroll
    for (int ks = 0; ks < 4; ks++) {
        const int c0 = ks * 8 + quad * 2;
        union { uint4 u[2]; float f[8]; } xv;
        xv.u[0] = xs[xrow][c0 ^ xrow];
        xv.u[1] = xs[xrow][(c0 + 1) ^ xrow];
        union { unsigned short us[8]; short8 v; } ahi, alo;
#pragma unroll
        for (int jj = 0; jj < 8; jj++) {
            unsigned short hi = f2bf(xv.f[jj]);
            ahi.us[jj] = hi;
            alo.us[jj] = f2bf(xv.f[jj] - bf2f(hi));
        }
#pragma unroll
        for (int ot = 0; ot < 4; ot++) {
            const int o = (oh * 4 + ot) * 16 + m;
            const float* wp = W + (size_t)o * FD + ks * 32 + quad * 8;
            float4 w0 = *(const float4*)wp;
            float4 w1 = *(const float4*)(wp + 4);
            union { unsigned short us[8]; short8 v; } bw;
            bw.us[0] = f2bf(w0.x); bw.us[1] = f2bf(w0.y);
            bw.us[2] = f2bf(w0.z); bw.us[3] = f2bf(w0.w);
            bw.us[4] = f2bf(w1.x); bw.us[5] = f2bf(w1.y);
            bw.us[6] = f2bf(w1.z); bw.us[7] = f2bf(w1.w);
            acc[ot] = __builtin_amdgcn_mfma_f32_16x16x32_bf16(ahi.v, bw.v, acc[ot], 0, 0, 0);
            acc[ot] = __builtin_amdgcn_mfma_f32_16x16x32_bf16(alo.v, bw.v, acc[ot], 0, 0, 0);
        }
    }

    // ---- epilogue: chunked hT store + s1/s2 ----
    const int gr = bid * 32 + rh * 16 + quad * 4;  // C rows gr..gr+3 (= j)
    const int bb = gr >> 11;
    const int jb = gr & (N_ - 1);
    const int kc = jb >> 6;
    const int jcl = (jb & 63) >> 3;
    const int off = jb & 7;                        // 0 or 4
    unsigned short* hTb = hT + (size_t)bb * FD * N_ + (size_t)kc * (CHUNK_U4 * 8);
    float s1p[4] = {0.f, 0.f, 0.f, 0.f};
    float s2p[4] = {0.f, 0.f, 0.f, 0.f};
#pragma unroll
    for (int ot = 0; ot < 4; ot++) {
        const int o = (oh * 4 + ot) * 16 + m;
        uint2 pk;
        pk.x = (uint32_t)f2bf(acc[ot][0]) | ((uint32_t)f2bf(acc[ot][1]) << 16);
        pk.y = (uint32_t)f2bf(acc[ot][2]) | ((uint32_t)f2bf(acc[ot][3]) << 16);
        *(uint2*)(hTb + (size_t)HC64(o, jcl) * 8 + off) = pk;
        float a1v = a[o], a2v = a[FD + o];
#pragma unroll
        for (int r = 0; r < 4; r++) {
            s1p[r] += acc[ot][r] * a1v;
            s2p[r] += acc[ot][r] * a2v;
        }
    }
#pragma unroll
    for (int offx = 8; offx >= 1; offx >>= 1) {
#pragma unroll
        for (int r = 0; r < 4; r++) {
            s1p[r] += __shfl_xor(s1p[r], offx);
            s2p[r] += __shfl_xor(s2p[r], offx);
        }
    }
    if (m == 0) {
#pragma unroll
        for (int r = 0; r < 4; r++) {
            s1c[oh][rh * 16 + quad * 4 + r] = s1p[r];
            s2c[oh][rh * 16 + quad * 4 + r] = s2p[r];
        }
    }
    __syncthreads();
    if (tid < 32) {
        s1o[bid * 32 + tid] = s1c[0][tid] + s1c[1][tid];
        s2o[bid * 32 + tid] = s2c[0][tid] + s2c[1][tid];
    }
}

// ---------------------------------------------------------------------------
// Kernel 2 v4: fused masked-softmax + PV, barrier-free main loop.
// 1024 blocks (b = bid&7, i0 = (bid>>3)*16) x 256 threads (4 waves).
// Wave w = j-quarter: rows [i0,+16), j [w*512,+512) = 8 chunks of 64.
// B-frags gathered directly from L2-resident hT (no LDS, no barriers).
// Combine 4 quarters via LDS at the end (one barrier).
// ---------------------------------------------------------------------------
__global__ __launch_bounds__(256, 3) void gat_attn(
    const int* __restrict__ adj,
    const unsigned short* __restrict__ hT,
    const float* __restrict__ s1,
    const float* __restrict__ s2,
    float* __restrict__ out)
{
    __shared__ float part[3][16][128];   // 24 KB quarter partials
    __shared__ float prs[3][16];         // quarter row-sums

    const int bid = blockIdx.x;
    const int b = bid & 7;
    const int i0 = (bid >> 3) * 16;
    const int tid = threadIdx.x;
    const int lane = tid & 63;
    const int w = tid >> 6;              // j-quarter
    const int m = lane & 15;
    const int quad = lane >> 4;

    const int irow = i0 + m;             // this lane's P row (A-frag m)
    const float s1v = s1[b * N_ + irow];
    const int* adjrow = adj + ((size_t)(b * N_ + irow)) * N_ + w * 512;
    const uint4* hTq = (const uint4*)(hT + (size_t)b * FD * N_)
                       + (size_t)w * 8 * CHUNK_U4;
    const float* s2b = s2 + b * N_ + w * 512;

    f32x4 acc[8];
#pragma unroll
    for (int ot = 0; ot < 8; ot++) acc[ot] = (f32x4){0.f, 0.f, 0.f, 0.f};
    float rs_loc = 0.f;

#pragma unroll 2
    for (int k = 0; k < 8; k++) {
        const int j0 = k * 64;
        // adj + s2 for this chunk (lane layout == A-frag layout)
        int4 A[4];
        float4 S[4];
#pragma unroll
        for (int ks = 0; ks < 2; ks++) {
            A[2 * ks]     = *(const int4*)(adjrow + j0 + ks * 32 + quad * 8);
            A[2 * ks + 1] = *(const int4*)(adjrow + j0 + ks * 32 + quad * 8 + 4);
            S[2 * ks]     = *(const float4*)(s2b + j0 + ks * 32 + quad * 8);
            S[2 * ks + 1] = *(const float4*)(s2b + j0 + ks * 32 + quad * 8 + 4);
        }
        const uint4* hc = hTq + (size_t)k * CHUNK_U4;
#pragma unroll
        for (int ks = 0; ks < 2; ks++) {
            float4 sa = S[2 * ks], sb = S[2 * ks + 1];
            float sarr[8] = {sa.x, sa.y, sa.z, sa.w, sb.x, sb.y, sb.z, sb.w};
            int4 A0 = A[2 * ks], A1 = A[2 * ks + 1];
            int aarr[8] = {A0.x, A0.y, A0.z, A0.w, A1.x, A1.y, A1.z, A1.w};
            union { unsigned short us[8]; short8 v; } af;
#pragma unroll
            for (int jj = 0; jj < 8; jj++) {
                float e = s1v + sarr[jj];
                e = (e > 0.f) ? e : (ALPHA_ * e);
                float p = (aarr[jj] > 0) ? __expf(e) : 0.f;
                rs_loc += p;
                af.us[jj] = f2bf(p);
            }
            const int jc = ks * 4 + quad;  // B-frag 16B-chunk index
#pragma unroll
            for (int ot = 0; ot < 8; ot++) {
                const int o = ot * 16 + m;  // B-frag n = lane&15
                union { uint4 u; short8 v; } bf;
                bf.u = hc[HC64(o, jc)];     // L2 gather, no LDS round-trip
                acc[ot] = __builtin_amdgcn_mfma_f32_16x16x32_bf16(af.v, bf.v, acc[ot], 0, 0, 0);
            }
        }
    }

    // ---- combine 4 j-quarters ----
    rs_loc += __shfl_xor(rs_loc, 16);    // all lanes: quarter sum for row m
    rs_loc += __shfl_xor(rs_loc, 32);
    if (w > 0) {
#pragma unroll
        for (int ot = 0; ot < 8; ot++)
#pragma unroll
            for (int r = 0; r < 4; r++)
                part[w - 1][quad * 4 + r][ot * 16 + m] = acc[ot][r];
        if (quad == 0) prs[w - 1][m] = rs_loc;
    }
    __syncthreads();
    if (w == 0) {
        float rinv[4];
#pragma unroll
        for (int r = 0; r < 4; r++) {
            const int p = quad * 4 + r;
            rinv[r] = 1.0f / (__shfl(rs_loc, p) + prs[0][p] + prs[1][p] + prs[2][p]);
        }
        float* outp = out + (size_t)(b * N_ + i0) * FD;
#pragma unroll
        for (int ot = 0; ot < 8; ot++) {
            const int col = ot * 16 + m;
#pragma unroll
            for (int r = 0; r < 4; r++) {
                const int row = quad * 4 + r;
                float v = acc[ot][r] + part[0][row][col] + part[1][row][col]
                                     + part[2][row][col];
                outp[(size_t)row * FD + col] = v * rinv[r];
            }
        }
    }
}

// ---------------------------------------------------------------------------
extern "C" void kernel_launch(void* const* d_in, const int* in_sizes, int n_in,
                              void* d_out, int out_size, void* d_ws, size_t ws_size,
                              hipStream_t stream) {
    const void* xv = d_in[0];
    const void* adjv = d_in[1];
    const void* Wv = d_in[2];
    const void* av = d_in[3];
    for (int i = 0; i < n_in; i++) {
        switch (in_sizes[i]) {
            case 2097152:  xv = d_in[i]; break;
            case 33554432: adjv = d_in[i]; break;
            case 16384:    Wv = d_in[i]; break;
            case 256:      av = d_in[i]; break;
            default: break;
        }
    }
    const float* x = (const float*)xv;
    const int* adj = (const int*)adjv;
    const float* W = (const float*)Wv;
    const float* a = (const float*)av;
    float* out = (float*)d_out;

    // ws: hT 4MB | s1 64KB | s2 64KB
    char* p = (char*)d_ws;
    unsigned short* hT = (unsigned short*)p;  p += (size_t)B_ * FD * N_ * 2;
    float* s1 = (float*)p;                    p += (size_t)B_ * N_ * 4;
    float* s2 = (float*)p;

    gat_h<<<512, 256, 0, stream>>>(x, W, a, hT, s1, s2);
    gat_attn<<<1024, 256, 0, stream>>>(adj, hT, s1, s2, out);
}